// Round 10
// baseline (83.137 us; speedup 1.0000x reference)
//
#include <hip/hip_runtime.h>

#define NBODY 8192
#define BLOCK 256
#define SLABS 32
#define JCHUNK (NBODY / SLABS)   // 256 j-bodies per block
#define PHASE 8                  // j-bodies per SGPR buffer
#define NPHASE (JCHUNK / PHASE)  // 32
#define PWPAD (PHASE)            // dead-prefetch overrun pad
#define SOFT2 1.0e-4f            // 0.01^2

// Pack (x,y,z,m) so the force loop's uniform j-reads are s_load_dwordx16.
__global__ __launch_bounds__(BLOCK) void pack_kernel(
    const float* __restrict__ pos, const float* __restrict__ mass,
    float4* __restrict__ pw) {
  const int i = blockIdx.x * BLOCK + threadIdx.x;
  pw[i] = make_float4(pos[i * 3 + 0], pos[i * 3 + 1], pos[i * 3 + 2], mass[i]);
}

#define PAIR(o)                                        \
  do {                                                 \
    float dx = (o).x - xi;                             \
    float dy = (o).y - yi;                             \
    float dz = (o).z - zi;                             \
    float r2 = fmaf(dx, dx, fmaf(dy, dy, fmaf(dz, dz, SOFT2))); \
    float inv = __builtin_amdgcn_rsqf(r2);             \
    float w = (o).w * ((inv * inv) * inv);             \
    ax = fmaf(w, dx, ax);                              \
    ay = fmaf(w, dy, ay);                              \
    az = fmaf(w, dz, az);                              \
  } while (0)

// Final DS-pipe test: j-bodies travel exclusively through the SCALAR pipe
// (uniform address -> s_load, values live in SGPRs; each VALU op reads at
// most one SGPR operand - legal). Explicit A/B double buffer with static
// indexing gives the prefetch a full phase (~224cy compute) to cover K$
// latency (~200cy) - R1's failure was 0 prefetch distance, not the pipe.
// No LDS, no __syncthreads, no ds_read: if the 10-round ~20us invariant
// stall is DS-broadcast serialization, it disappears here.
__global__ __launch_bounds__(BLOCK, 4) void force_kernel(
    const float4* __restrict__ pw, const float* __restrict__ pos,
    float* __restrict__ out) {
  const int t = threadIdx.x;
  const int i = blockIdx.x * BLOCK + t;
  const float4* __restrict__ pj = pw + blockIdx.y * JCHUNK;  // uniform base

  const float xi = pos[i * 3 + 0];
  const float yi = pos[i * 3 + 1];
  const float zi = pos[i * 3 + 2];

  float ax = 0.f, ay = 0.f, az = 0.f;

  float4 A[PHASE], B[PHASE];
#pragma unroll
  for (int u = 0; u < PHASE; ++u) A[u] = pj[u];  // prologue: phase 0 -> A

  // 32 phases, processed two per iteration (A then B), all indices static.
  for (int c = 0; c < NPHASE; c += 2) {
#pragma unroll
    for (int u = 0; u < PHASE; ++u) B[u] = pj[(c + 1) * PHASE + u];
#pragma unroll
    for (int u = 0; u < PHASE; ++u) PAIR(A[u]);
#pragma unroll
    for (int u = 0; u < PHASE; ++u)
      A[u] = pj[(c + 2) * PHASE + u];  // last iter overruns into pad (unused)
#pragma unroll
    for (int u = 0; u < PHASE; ++u) PAIR(B[u]);
  }

  // 32 slabs contend per address (R0/R9-proven; L2-side float adds).
  atomicAdd(&out[i * 3 + 0], ax);
  atomicAdd(&out[i * 3 + 1], ay);
  atomicAdd(&out[i * 3 + 2], az);
}

extern "C" void kernel_launch(void* const* d_in, const int* in_sizes, int n_in,
                              void* d_out, int out_size, void* d_ws,
                              size_t ws_size, hipStream_t stream) {
  const float* pos = (const float*)d_in[0];
  const float* mass = (const float*)d_in[1];
  float* out = (float*)d_out;
  float4* pw = (float4*)d_ws;  // NBODY+PWPAD entries; pad absorbs dead loads

  // d_out is re-poisoned to 0xAA before every launch; atomics need zeros.
  hipMemsetAsync(d_out, 0, (size_t)out_size * sizeof(float), stream);

  pack_kernel<<<NBODY / BLOCK, BLOCK, 0, stream>>>(pos, mass, pw);
  force_kernel<<<dim3(NBODY / BLOCK, SLABS), BLOCK, 0, stream>>>(pw, pos, out);
}

// Round 12
// 79.593 us; speedup vs baseline: 1.0445x; 1.0445x over previous
//
#include <hip/hip_runtime.h>

#define NBODY 8192
#define BLOCK 256
#define SLABS 16                 // j-slabs -> grid (32,16) = 512 blocks
#define JCHUNK (NBODY / SLABS)   // 512 j-bodies per block
#define SPT (JCHUNK / BLOCK)     // 2 staged per thread
#define PHASE 16                 // j-bodies register-hoisted per burst
#define NPHASE (JCHUNK / PHASE)  // 32
#define SOFT2 1.0e-4f            // 0.01^2

// R9 structure (best: 78.2) with ONE variable: 2 blocks/CU = 2 waves/SIMD
// (was 4). Rationale: 11-config ledger pins force at ~85 cy/wave-pair-unit,
// VALUBusy ~36%, with issue model ~26-40 cy. R3 showed 8 waves/SIMD is ~7%
// WORSE than 4 -> resident-wave contention on the issue port. 4->2 is the
// untested end of that trend; also halves atomic contention (32->16-way).
// Same total pair-units/SIMD (2 waves x 512 j = 1024), same 12-op+v_rsq pair
// (R7: v_rsq ~free, trans pipe exonerated), same burst-hoist (R4: -3us).
__global__ __launch_bounds__(BLOCK, 2) void nbody_kernel(
    const float* __restrict__ pos, const float* __restrict__ mass,
    float* __restrict__ out) {
  __shared__ float4 tile[JCHUNK];  // 8 KB

  const int t = threadIdx.x;
  const int i = blockIdx.x * BLOCK + t;
  const int j0 = blockIdx.y * JCHUNK;

  // Stage j-slab: 2 bodies per thread.
#pragma unroll
  for (int s = 0; s < SPT; ++s) {
    const int j = j0 + s * BLOCK + t;
    tile[s * BLOCK + t] = make_float4(pos[j * 3 + 0], pos[j * 3 + 1],
                                      pos[j * 3 + 2], mass[j]);
  }

  const float xi = pos[i * 3 + 0];
  const float yi = pos[i * 3 + 1];
  const float zi = pos[i * 3 + 2];

  __syncthreads();

  float ax = 0.f, ay = 0.f, az = 0.f;

  for (int c = 0; c < NPHASE; ++c) {
    // Burst-hoist one phase of j-bodies into registers: 16 independent
    // wave-uniform ds_read_b128, single lgkm wait (R4-proven).
    float4 jt[PHASE];
#pragma unroll
    for (int u = 0; u < PHASE; ++u) jt[u] = tile[c * PHASE + u];

    // Pure-register compute: 12 full-rate ops + 1 trans per pair.
#pragma unroll
    for (int u = 0; u < PHASE; ++u) {
      float dx = jt[u].x - xi;
      float dy = jt[u].y - yi;
      float dz = jt[u].z - zi;
      float r2 = fmaf(dx, dx, fmaf(dy, dy, fmaf(dz, dz, SOFT2)));
      float inv = __builtin_amdgcn_rsqf(r2);   // v_rsq_f32
      float w = jt[u].w * ((inv * inv) * inv); // m_j * r^-3
      ax = fmaf(w, dx, ax);
      ay = fmaf(w, dy, ay);
      az = fmaf(w, dz, az);
    }
  }

  // 16 slabs contend per address (half of R9's 32; L2-side float adds).
  atomicAdd(&out[i * 3 + 0], ax);
  atomicAdd(&out[i * 3 + 1], ay);
  atomicAdd(&out[i * 3 + 2], az);
}

extern "C" void kernel_launch(void* const* d_in, const int* in_sizes, int n_in,
                              void* d_out, int out_size, void* d_ws,
                              size_t ws_size, hipStream_t stream) {
  const float* pos = (const float*)d_in[0];
  const float* mass = (const float*)d_in[1];
  float* out = (float*)d_out;

  // d_out is re-poisoned to 0xAA before every launch; atomics need zeros.
  hipMemsetAsync(d_out, 0, (size_t)out_size * sizeof(float), stream);

  nbody_kernel<<<dim3(NBODY / BLOCK, SLABS), BLOCK, 0, stream>>>(pos, mass,
                                                                 out);
}